// Round 22
// baseline (599.260 us; speedup 1.0000x reference)
//
#include <hip/hip_runtime.h>

typedef __attribute__((ext_vector_type(8))) short short8;
typedef __attribute__((ext_vector_type(4))) short short4v;
typedef __attribute__((ext_vector_type(4))) float f32x4;

#define MFMA(a, b, c) __builtin_amdgcn_mfma_f32_16x16x32_bf16((a), (b), (c), 0, 0, 0)
#define GLD16(g, l)                                                            \
  __builtin_amdgcn_global_load_lds(                                            \
      (const __attribute__((address_space(1))) void*)(g),                      \
      (__attribute__((address_space(3))) void*)(l), 16, 0, 0)

static __device__ __forceinline__ float b2f(unsigned short b) {
  union { unsigned u; float f; } u; u.u = ((unsigned)b) << 16; return u.f;
}
static __device__ __forceinline__ unsigned short f2b(float f) {
  union { float f; unsigned u; } u; u.f = f;
  unsigned r = u.u + 0x7FFFu + ((u.u >> 16) & 1u);
  return (unsigned short)(r >> 16);
}
// HW RNE pack: low16 = bf16(a), high16 = bf16(b). Same rounding as f2b.
static __device__ __forceinline__ unsigned cvt_pk_bf16(float a, float b) {
  unsigned r;
  asm("v_cvt_pk_bf16_f32 %0, %1, %2" : "=v"(r) : "v"(a), "v"(b));
  return r;
}

// fp32 -> bf16 convert: [hidden][q_w][k_w][v_w][o_w] -> contiguous bf16.
__global__ __launch_bounds__(256) void convert_kernel(
    const float* __restrict__ hidden,
    const float* __restrict__ qw, const float* __restrict__ kw,
    const float* __restrict__ vw, const float* __restrict__ ow,
    unsigned short* __restrict__ dst) {
  const int HID4 = 2097152, W4 = 262144, TOT = HID4 + 4 * W4;
  for (int i = blockIdx.x * 256 + threadIdx.x; i < TOT; i += gridDim.x * 256) {
    const float* src; int off;
    if (i < HID4) { src = hidden; off = i; }
    else {
      int j = i - HID4; int w = j >> 18; off = j & (W4 - 1);
      src = (w == 0) ? qw : (w == 1) ? kw : (w == 2) ? vw : ow;
    }
    float4 v = *(const float4*)&src[(size_t)off * 4];
    short4v s;
    s[0] = (short)f2b(v.x); s[1] = (short)f2b(v.y);
    s[2] = (short)f2b(v.z); s[3] = (short)f2b(v.w);
    *(short4v*)&dst[(size_t)i * 4] = s;
  }
}

// C[8192 x N] = A[8192 x 1024](bf16) * W^T (W [N x 1024] bf16 row-major).
// 256x128 tile, BK=32, 512 thr (8 waves 4Mx2N), 2 LDS buffers (48KB ->
// 3 blocks/CU; grid 768 = exactly 3/CU, single uniform round). m97 pattern:
// stage t+1 early, vmcnt(0)+barrier per tile, drain covered by 3-way block
// overlap. Swizzle f(ra)=(ra>>1)&3 (2-way aliasing, free). QKV=true: RoPE
// epilogue with direct global cos/sin reads (L2-resident).
template <bool QKV>
__global__ __launch_bounds__(512, 6) void gemm256(
    const unsigned short* __restrict__ A,
    const unsigned short* __restrict__ W,
    void* __restrict__ Cv,
    const float* __restrict__ cosb, const float* __restrict__ sinb) {
  __shared__ __align__(16) unsigned short lds[24576];  // 2 x (A 8192 + B 4096)
  const int tid = threadIdx.x, wave = tid >> 6, lane = tid & 63;
  const int bm = blockIdx.x << 8, bnc = blockIdx.y << 7;
  const int wr = (wave >> 1) << 6, wc = (wave & 1) << 6;
  const int lr = lane & 15, hi4 = lane >> 4;
  const int rowb = tid >> 2;                        // 0..127
  const int cgA = (tid & 3) ^ ((rowb >> 1) & 3);    // pre-swizzled source col-group
  const unsigned short* aSrc = A + (size_t)(bm + rowb) * 1024 + (cgA << 3);
  const unsigned short* bSrc = W + (size_t)(bnc + rowb) * 1024 + (cgA << 3);

  f32x4 acc[4][4] = {};

#define STAGE(t, bi)                                                           \
  do {                                                                         \
    unsigned short* As_ = lds + (bi) * 12288;                                  \
    unsigned short* Bs_ = As_ + 8192;                                          \
    const int k0_ = (t) << 5;                                                  \
    _Pragma("unroll") for (int i = 0; i < 2; ++i)                              \
        GLD16(aSrc + (size_t)(i << 7) * 1024 + k0_,                            \
              As_ + (((i << 9) + tid) << 3));                                  \
    GLD16(bSrc + k0_, Bs_ + (tid << 3));                                       \
  } while (0)

  STAGE(0, 0);
  asm volatile("s_waitcnt vmcnt(0)" ::: "memory");  // tile 0 landed
  __builtin_amdgcn_s_barrier();
  __builtin_amdgcn_sched_barrier(0);

  int bi = 0;
#pragma unroll
  for (int t = 0; t < 32; ++t) {
    if (t < 31) STAGE(t + 1, bi ^ 1);  // issue early; lands during compute
    const unsigned short* As = lds + bi * 12288;
    const unsigned short* Bs = As + 8192;
    short8 af[4], bfr[4];
#pragma unroll
    for (int x = 0; x < 4; ++x) {
      int ra = wr + x * 16 + lr;
      af[x] = *(const short8*)&As[ra * 32 + ((hi4 ^ ((ra >> 1) & 3)) << 3)];
      int rb = wc + x * 16 + lr;
      bfr[x] = *(const short8*)&Bs[rb * 32 + ((hi4 ^ ((rb >> 1) & 3)) << 3)];
    }
    __builtin_amdgcn_s_setprio(1);
#pragma unroll
    for (int mm = 0; mm < 4; ++mm)
#pragma unroll
      for (int nn = 0; nn < 4; ++nn)
        acc[mm][nn] = MFMA(af[mm], bfr[nn], acc[mm][nn]);
    __builtin_amdgcn_s_setprio(0);
    __builtin_amdgcn_sched_barrier(0);
    asm volatile("s_waitcnt vmcnt(0)" ::: "memory");  // t+1 landed (drain;
    __builtin_amdgcn_s_barrier();                     //  covered by 3 blocks/CU)
    __builtin_amdgcn_sched_barrier(0);
    bi ^= 1;
  }
#undef STAGE

  const int rg = hi4 << 2;
  if constexpr (QKV) {
    const int grp = bnc >> 10;  // 0=Q 1=K 2=V
    unsigned short* Cbuf = (unsigned short*)Cv + (size_t)grp * 8388608;
    const int colbase = (bnc & 1023) + wc;
    if (grp < 2) {
      // RoPE epilogue; cos/sin read directly from global (L2-resident 4MB).
      const float sc = (grp == 0) ? 0.18033688011112042f : 1.0f;  // 0.125*log2e
#pragma unroll
      for (int mm = 0; mm < 4; ++mm)
#pragma unroll
        for (int r = 0; r < 4; ++r) {
          int rloc = wr + mm * 16 + rg + r;
          size_t rowoff = (size_t)(bm + rloc) * 1024;
          size_t csoff = (size_t)(bm + rloc) * 64;
#pragma unroll
          for (int nn = 0; nn < 2; ++nn) {
            int d = nn * 16 + lr;
            float c = cosb[csoff + d], s2 = sinb[csoff + d];
            float lo = acc[mm][nn][r], hi = acc[mm][nn + 2][r];
            Cbuf[rowoff + colbase + nn * 16 + lr]      = f2b((lo * c - hi * s2) * sc);
            Cbuf[rowoff + colbase + nn * 16 + lr + 32] = f2b((hi * c + lo * s2) * sc);
          }
        }
    } else {
#pragma unroll
      for (int mm = 0; mm < 4; ++mm)
#pragma unroll
        for (int nn = 0; nn < 4; ++nn)
#pragma unroll
          for (int r = 0; r < 4; ++r)
            Cbuf[(size_t)(bm + wr + mm * 16 + rg + r) * 1024 + colbase + nn * 16 + lr] =
                f2b(acc[mm][nn][r]);
    }
  } else {
    float* C = (float*)Cv;
#pragma unroll
    for (int mm = 0; mm < 4; ++mm)
#pragma unroll
      for (int nn = 0; nn < 4; ++nn)
#pragma unroll
        for (int r = 0; r < 4; ++r)
          C[(size_t)(bm + wr + mm * 16 + rg + r) * 1024 + bnc + wc + nn * 16 + lr] =
              acc[mm][nn][r];
  }
}

// Causal flash attention v11 (round-18 exact, best measured): 1024-block LPT,
// 3 blocks/CU, swapped-QK^T in-register softmax, cvt_pk pack, permuted V,
// KVBLK=64 dbuf, lazy row-max, per-lane partial l, exp2 domain.
__global__ __launch_bounds__(256, 3) void attn_kernel(
    const unsigned short* __restrict__ Q,
    const unsigned short* __restrict__ K,
    const unsigned short* __restrict__ V,
    unsigned short* __restrict__ O) {
  __shared__ unsigned short Ks[2][64][72];   // [buf][key][d]
  __shared__ unsigned short Vt[2][64][72];   // [buf][d][permuted key col]
  const int tid = threadIdx.x, wave = tid >> 6, lane = tid & 63;
  const int idx = blockIdx.x;
  const int bh = idx & 127;
  const int b = bh >> 4, h = bh & 15;
  const int qb = 7 - (idx >> 7);             // heavy-first (LPT)
  const int tok0 = b << 10;
  const int lr = lane & 15, hi4 = lane >> 4, lk8 = hi4 << 3;
  const int rg = hi4 << 2;
  const int qrow0 = (qb << 7) + (wave << 5); // 32 rows per wave

  short8 qf[2][2];
#pragma unroll
  for (int mt = 0; mt < 2; ++mt) {
    const unsigned short* qp = &Q[(size_t)(tok0 + qrow0 + mt * 16 + lr) * 1024 + h * 64];
#pragma unroll
    for (int kk = 0; kk < 2; ++kk) qf[mt][kk] = *(const short8*)&qp[kk * 32 + lk8];
  }

  f32x4 acc[2][4] = {};
  float m[2], l[2];                          // l = per-lane partial
#pragma unroll
  for (int mt = 0; mt < 2; ++mt) { m[mt] = -1e30f; l[mt] = 0.f; }

  const int krow = tid >> 3, kcol = (tid & 7) << 3;  // K: rows krow, krow+32
  const int vd = lane;                               // V: d index
  const int baseC = ((wave & 1) << 4) + ((wave >> 1) << 2);  // perm col base
  short8 kst[2];
  short4v vst[4];

#define LOADT(kbx)                                                                 \
  do {                                                                             \
    const int kr0_ = tok0 + ((kbx) << 6);                                          \
    _Pragma("unroll") for (int it = 0; it < 2; ++it)                               \
        kst[it] = *(const short8*)&K[(size_t)(kr0_ + krow + it * 32) * 1024 +      \
                                     h * 64 + kcol];                               \
    _Pragma("unroll") for (int it = 0; it < 2; ++it) {                             \
      const unsigned short* vp_ =                                                  \
          &V[(size_t)(kr0_ + ((wave + it * 4) << 3)) * 1024 + h * 64 + vd];        \
      _Pragma("unroll") for (int i = 0; i < 4; ++i) {                              \
        vst[it * 2][i]     = (short)vp_[(size_t)i * 1024];                         \
        vst[it * 2 + 1][i] = (short)vp_[(size_t)(i + 4) * 1024];                   \
      }                                                                            \
    }                                                                              \
  } while (0)

#define STORET(bi)                                                                 \
  do {                                                                             \
    _Pragma("unroll") for (int it = 0; it < 2; ++it)                               \
        *(short8*)&Ks[bi][krow + it * 32][kcol] = kst[it];                         \
    *(short4v*)&Vt[bi][vd][baseC]          = vst[0];                               \
    *(short4v*)&Vt[bi][vd][baseC + 8]      = vst[1];                               \
    *(short4v*)&Vt[bi][vd][32 + baseC]     = vst[2];                               \
    *(short4v*)&Vt[bi][vd][32 + baseC + 8] = vst[3];                               \
  } while (0)

  const int nkb = (qb + 1) << 1;
  LOADT(0);
  STORET(0);
  __syncthreads();

  for (int kb = 0; kb < nkb; ++kb) {
    const int cur = kb & 1;
    const bool more = (kb + 1 < nkb);
    if (more) LOADT(kb + 1);  // VMEM in flight during compute (T14)

    // QK^T for BOTH m-tiles: kf read once (8 ds_reads, shared)
    float p[2][4][4];
#pragma unroll
    for (int ct = 0; ct < 4; ++ct) {
      short8 kf0 = *(const short8*)&Ks[cur][ct * 16 + lr][lk8];
      short8 kf1 = *(const short8*)&Ks[cur][ct * 16 + lr][32 + lk8];
      f32x4 s0 = {}, s1 = {};
      s0 = MFMA(kf0, qf[0][0], s0);
      s0 = MFMA(kf1, qf[0][1], s0);
      s1 = MFMA(kf0, qf[1][0], s1);
      s1 = MFMA(kf1, qf[1][1], s1);
#pragma unroll
      for (int r = 0; r < 4; ++r) { p[0][ct][r] = s0[r]; p[1][ct][r] = s1[r]; }
    }
    if (kb >= 2 * qb) {  // diagonal region: mask key > q
#pragma unroll
      for (int mt = 0; mt < 2; ++mt) {
        const int qg = qrow0 + mt * 16 + lr;
#pragma unroll
        for (int ct = 0; ct < 4; ++ct)
#pragma unroll
          for (int r = 0; r < 4; ++r) {
            int kg = (kb << 6) + ct * 16 + rg + r;
            if (kg > qg) p[mt][ct][r] = -1e30f;
          }
      }
    }
    // softmax: lazy row-max + per-lane partial l (no cross-lane common path)
    unsigned pk[2][4][2];
#pragma unroll
    for (int mt = 0; mt < 2; ++mt) {
      float lmx = p[mt][0][0];   // lane-local max (16 own values)
#pragma unroll
      for (int ct = 0; ct < 4; ++ct)
#pragma unroll
        for (int r = 0; r < 4; ++r) lmx = fmaxf(lmx, p[mt][ct][r]);
      if (__any(lmx > m[mt] + 8.f)) {
        float mx = lmx;
        mx = fmaxf(mx, __shfl_xor(mx, 16));
        mx = fmaxf(mx, __shfl_xor(mx, 32));
        float mn = fmaxf(m[mt], mx);
        float alpha = __builtin_amdgcn_exp2f(m[mt] - mn);
        m[mt] = mn;
        l[mt] *= alpha;
        float a4[4];
#pragma unroll
        for (int r = 0; r < 4; ++r) a4[r] = __shfl(alpha, rg + r);
#pragma unroll
        for (int dt = 0; dt < 4; ++dt)
#pragma unroll
          for (int r = 0; r < 4; ++r) acc[mt][dt][r] *= a4[r];
      }
      float rs = 0.f;
#pragma unroll
      for (int ct = 0; ct < 4; ++ct) {
#pragma unroll
        for (int r = 0; r < 4; ++r) {
          p[mt][ct][r] = __builtin_amdgcn_exp2f(p[mt][ct][r] - m[mt]);
          rs += p[mt][ct][r];
        }
        pk[mt][ct][0] = cvt_pk_bf16(p[mt][ct][0], p[mt][ct][1]);
        pk[mt][ct][1] = cvt_pk_bf16(p[mt][ct][2], p[mt][ct][3]);
      }
      l[mt] += rs;               // lane-local partial; reduced once at the end
    }
    // PV for BOTH m-tiles: vf read once (8 ds_reads, shared)
#pragma unroll
    for (int kk = 0; kk < 2; ++kk) {
      union { unsigned u[4]; short8 v; } pa0, pa1;
      pa0.u[0] = pk[0][kk * 2][0];     pa0.u[1] = pk[0][kk * 2][1];
      pa0.u[2] = pk[0][kk * 2 + 1][0]; pa0.u[3] = pk[0][kk * 2 + 1][1];
      pa1.u[0] = pk[1][kk * 2][0];     pa1.u[1] = pk[1][kk * 2][1];
      pa1.u[2] = pk[1][kk * 2 + 1][0]; pa1.u[3] = pk[1][kk * 2 + 1][1];
#pragma unroll
      for (int dt = 0; dt < 4; ++dt) {
        short8 vf = *(const short8*)&Vt[cur][dt * 16 + lr][kk * 32 + lk8];
        acc[0][dt] = MFMA(pa0.v, vf, acc[0][dt]);
        acc[1][dt] = MFMA(pa1.v, vf, acc[1][dt]);
      }
    }

    if (more) {
      STORET(cur ^ 1);
      __syncthreads();
    }
  }
#undef LOADT
#undef STORET

#pragma unroll
  for (int mt = 0; mt < 2; ++mt) {
    float lsum = l[mt];
    lsum += __shfl_xor(lsum, 16);
    lsum += __shfl_xor(lsum, 32);
    float linv = 1.0f / lsum;
    float inv[4];
#pragma unroll
    for (int r = 0; r < 4; ++r) inv[r] = __shfl(linv, rg + r);
#pragma unroll
    for (int dt = 0; dt < 4; ++dt)
#pragma unroll
      for (int r = 0; r < 4; ++r) {
        int trow = tok0 + qrow0 + mt * 16 + rg + r;
        O[(size_t)trow * 1024 + h * 64 + dt * 16 + lr] = f2b(acc[mt][dt][r] * inv[r]);
      }
  }
}

extern "C" void kernel_launch(void* const* d_in, const int* in_sizes, int n_in,
                              void* d_out, int out_size, void* d_ws, size_t ws_size,
                              hipStream_t stream) {
  const float* hidden = (const float*)d_in[0];
  const float* q_w    = (const float*)d_in[1];
  const float* k_w    = (const float*)d_in[2];
  const float* v_w    = (const float*)d_in[3];
  const float* o_w    = (const float*)d_in[4];
  const float* cosb   = (const float*)d_in[5];
  const float* sinb   = (const float*)d_in[6];

  const size_t TD = (size_t)8192 * 1024;
  unsigned short* ws  = (unsigned short*)d_ws;
  unsigned short* Qb  = ws;
  unsigned short* Kb  = ws + TD;
  unsigned short* Vb  = ws + 2 * TD;
  unsigned short* hBF = ws + 3 * TD;        // hidden bf16; aliased as AO after QKV
  unsigned short* wBF = ws + 4 * TD;        // q,k,v,o weights bf16 (4 x 1M)

  convert_kernel<<<4096, 256, 0, stream>>>(hidden, q_w, k_w, v_w, o_w, hBF);
  gemm256<true><<<dim3(32, 24), 512, 0, stream>>>(hBF, wBF, Qb, cosb, sinb);
  attn_kernel<<<1024, 256, 0, stream>>>(Qb, Kb, Vb, hBF /*AO*/);
  gemm256<false><<<dim3(32, 8), 512, 0, stream>>>(
      hBF, wBF + 3 * 1048576, d_out, nullptr, nullptr);
}

// Round 23
// 130.581 us; speedup vs baseline: 4.5892x; 4.5892x over previous
//
#include <hip/hip_runtime.h>

typedef __attribute__((ext_vector_type(8))) short short8;
typedef __attribute__((ext_vector_type(4))) short short4v;
typedef __attribute__((ext_vector_type(4))) float f32x4;

#define MFMA(a, b, c) __builtin_amdgcn_mfma_f32_16x16x32_bf16((a), (b), (c), 0, 0, 0)
#define GLD16(g, l)                                                            \
  __builtin_amdgcn_global_load_lds(                                            \
      (const __attribute__((address_space(1))) void*)(g),                      \
      (__attribute__((address_space(3))) void*)(l), 16, 0, 0)

static __device__ __forceinline__ float b2f(unsigned short b) {
  union { unsigned u; float f; } u; u.u = ((unsigned)b) << 16; return u.f;
}
static __device__ __forceinline__ unsigned short f2b(float f) {
  union { float f; unsigned u; } u; u.f = f;
  unsigned r = u.u + 0x7FFFu + ((u.u >> 16) & 1u);
  return (unsigned short)(r >> 16);
}
// HW RNE pack: low16 = bf16(a), high16 = bf16(b). Same rounding as f2b.
static __device__ __forceinline__ unsigned cvt_pk_bf16(float a, float b) {
  unsigned r;
  asm("v_cvt_pk_bf16_f32 %0, %1, %2" : "=v"(r) : "v"(a), "v"(b));
  return r;
}

// fp32 -> bf16 convert: [hidden][q_w][k_w][v_w][o_w] -> contiguous bf16.
__global__ __launch_bounds__(256) void convert_kernel(
    const float* __restrict__ hidden,
    const float* __restrict__ qw, const float* __restrict__ kw,
    const float* __restrict__ vw, const float* __restrict__ ow,
    unsigned short* __restrict__ dst) {
  const int HID4 = 2097152, W4 = 262144, TOT = HID4 + 4 * W4;
  for (int i = blockIdx.x * 256 + threadIdx.x; i < TOT; i += gridDim.x * 256) {
    const float* src; int off;
    if (i < HID4) { src = hidden; off = i; }
    else {
      int j = i - HID4; int w = j >> 18; off = j & (W4 - 1);
      src = (w == 0) ? qw : (w == 1) ? kw : (w == 2) ? vw : ow;
    }
    float4 v = *(const float4*)&src[(size_t)off * 4];
    short4v s;
    s[0] = (short)f2b(v.x); s[1] = (short)f2b(v.y);
    s[2] = (short)f2b(v.z); s[3] = (short)f2b(v.w);
    *(short4v*)&dst[(size_t)i * 4] = s;
  }
}

// C[8192 x N] = A[8192 x 1024](bf16) * W^T (W [N x 1024] bf16 row-major).
// 256x128 tile, BK=32, 512 thr (8 waves 4Mx2N), 2 LDS buffers (48KB ->
// LDS-limited 3 blocks/CU at natural ~64 VGPR; grid 768 = exactly 3/CU,
// single uniform round). m97 pattern: stage t+1 early, vmcnt(0)+barrier per
// tile, drain covered by 3-way block overlap. Swizzle f(ra)=(ra>>1)&3.
// QKV=true: RoPE epilogue with direct global cos/sin reads (L2-resident).
// NOTE: launch_bounds min-waves arg kept at 4 — pinning 6 forced a 40-VGPR
// allocation and spilled acc to scratch (round-22: 2.2GB scratch traffic).
template <bool QKV>
__global__ __launch_bounds__(512, 4) void gemm256(
    const unsigned short* __restrict__ A,
    const unsigned short* __restrict__ W,
    void* __restrict__ Cv,
    const float* __restrict__ cosb, const float* __restrict__ sinb) {
  __shared__ __align__(16) unsigned short lds[24576];  // 2 x (A 8192 + B 4096)
  const int tid = threadIdx.x, wave = tid >> 6, lane = tid & 63;
  const int bm = blockIdx.x << 8, bnc = blockIdx.y << 7;
  const int wr = (wave >> 1) << 6, wc = (wave & 1) << 6;
  const int lr = lane & 15, hi4 = lane >> 4;
  const int rowb = tid >> 2;                        // 0..127
  const int cgA = (tid & 3) ^ ((rowb >> 1) & 3);    // pre-swizzled source col-group
  const unsigned short* aSrc = A + (size_t)(bm + rowb) * 1024 + (cgA << 3);
  const unsigned short* bSrc = W + (size_t)(bnc + rowb) * 1024 + (cgA << 3);

  f32x4 acc[4][4] = {};

#define STAGE(t, bi)                                                           \
  do {                                                                         \
    unsigned short* As_ = lds + (bi) * 12288;                                  \
    unsigned short* Bs_ = As_ + 8192;                                          \
    const int k0_ = (t) << 5;                                                  \
    _Pragma("unroll") for (int i = 0; i < 2; ++i)                              \
        GLD16(aSrc + (size_t)(i << 7) * 1024 + k0_,                            \
              As_ + (((i << 9) + tid) << 3));                                  \
    GLD16(bSrc + k0_, Bs_ + (tid << 3));                                       \
  } while (0)

  STAGE(0, 0);
  asm volatile("s_waitcnt vmcnt(0)" ::: "memory");  // tile 0 landed
  __builtin_amdgcn_s_barrier();
  __builtin_amdgcn_sched_barrier(0);

  int bi = 0;
#pragma unroll
  for (int t = 0; t < 32; ++t) {
    if (t < 31) STAGE(t + 1, bi ^ 1);  // issue early; lands during compute
    const unsigned short* As = lds + bi * 12288;
    const unsigned short* Bs = As + 8192;
    short8 af[4], bfr[4];
#pragma unroll
    for (int x = 0; x < 4; ++x) {
      int ra = wr + x * 16 + lr;
      af[x] = *(const short8*)&As[ra * 32 + ((hi4 ^ ((ra >> 1) & 3)) << 3)];
      int rb = wc + x * 16 + lr;
      bfr[x] = *(const short8*)&Bs[rb * 32 + ((hi4 ^ ((rb >> 1) & 3)) << 3)];
    }
    __builtin_amdgcn_s_setprio(1);
#pragma unroll
    for (int mm = 0; mm < 4; ++mm)
#pragma unroll
      for (int nn = 0; nn < 4; ++nn)
        acc[mm][nn] = MFMA(af[mm], bfr[nn], acc[mm][nn]);
    __builtin_amdgcn_s_setprio(0);
    __builtin_amdgcn_sched_barrier(0);
    asm volatile("s_waitcnt vmcnt(0)" ::: "memory");  // t+1 landed (drain;
    __builtin_amdgcn_s_barrier();                     //  covered by 3 blocks/CU)
    __builtin_amdgcn_sched_barrier(0);
    bi ^= 1;
  }
#undef STAGE

  const int rg = hi4 << 2;
  if constexpr (QKV) {
    const int grp = bnc >> 10;  // 0=Q 1=K 2=V
    unsigned short* Cbuf = (unsigned short*)Cv + (size_t)grp * 8388608;
    const int colbase = (bnc & 1023) + wc;
    if (grp < 2) {
      // RoPE epilogue; cos/sin read directly from global (L2-resident 4MB).
      const float sc = (grp == 0) ? 0.18033688011112042f : 1.0f;  // 0.125*log2e
#pragma unroll
      for (int mm = 0; mm < 4; ++mm)
#pragma unroll
        for (int r = 0; r < 4; ++r) {
          int rloc = wr + mm * 16 + rg + r;
          size_t rowoff = (size_t)(bm + rloc) * 1024;
          size_t csoff = (size_t)(bm + rloc) * 64;
#pragma unroll
          for (int nn = 0; nn < 2; ++nn) {
            int d = nn * 16 + lr;
            float c = cosb[csoff + d], s2 = sinb[csoff + d];
            float lo = acc[mm][nn][r], hi = acc[mm][nn + 2][r];
            Cbuf[rowoff + colbase + nn * 16 + lr]      = f2b((lo * c - hi * s2) * sc);
            Cbuf[rowoff + colbase + nn * 16 + lr + 32] = f2b((hi * c + lo * s2) * sc);
          }
        }
    } else {
#pragma unroll
      for (int mm = 0; mm < 4; ++mm)
#pragma unroll
        for (int nn = 0; nn < 4; ++nn)
#pragma unroll
          for (int r = 0; r < 4; ++r)
            Cbuf[(size_t)(bm + wr + mm * 16 + rg + r) * 1024 + colbase + nn * 16 + lr] =
                f2b(acc[mm][nn][r]);
    }
  } else {
    float* C = (float*)Cv;
#pragma unroll
    for (int mm = 0; mm < 4; ++mm)
#pragma unroll
      for (int nn = 0; nn < 4; ++nn)
#pragma unroll
        for (int r = 0; r < 4; ++r)
          C[(size_t)(bm + wr + mm * 16 + rg + r) * 1024 + bnc + wc + nn * 16 + lr] =
              acc[mm][nn][r];
  }
}

// Causal flash attention v11 (round-18 exact, best measured): 1024-block LPT,
// 3 blocks/CU, swapped-QK^T in-register softmax, cvt_pk pack, permuted V,
// KVBLK=64 dbuf, lazy row-max, per-lane partial l, exp2 domain.
__global__ __launch_bounds__(256, 3) void attn_kernel(
    const unsigned short* __restrict__ Q,
    const unsigned short* __restrict__ K,
    const unsigned short* __restrict__ V,
    unsigned short* __restrict__ O) {
  __shared__ unsigned short Ks[2][64][72];   // [buf][key][d]
  __shared__ unsigned short Vt[2][64][72];   // [buf][d][permuted key col]
  const int tid = threadIdx.x, wave = tid >> 6, lane = tid & 63;
  const int idx = blockIdx.x;
  const int bh = idx & 127;
  const int b = bh >> 4, h = bh & 15;
  const int qb = 7 - (idx >> 7);             // heavy-first (LPT)
  const int tok0 = b << 10;
  const int lr = lane & 15, hi4 = lane >> 4, lk8 = hi4 << 3;
  const int rg = hi4 << 2;
  const int qrow0 = (qb << 7) + (wave << 5); // 32 rows per wave

  short8 qf[2][2];
#pragma unroll
  for (int mt = 0; mt < 2; ++mt) {
    const unsigned short* qp = &Q[(size_t)(tok0 + qrow0 + mt * 16 + lr) * 1024 + h * 64];
#pragma unroll
    for (int kk = 0; kk < 2; ++kk) qf[mt][kk] = *(const short8*)&qp[kk * 32 + lk8];
  }

  f32x4 acc[2][4] = {};
  float m[2], l[2];                          // l = per-lane partial
#pragma unroll
  for (int mt = 0; mt < 2; ++mt) { m[mt] = -1e30f; l[mt] = 0.f; }

  const int krow = tid >> 3, kcol = (tid & 7) << 3;  // K: rows krow, krow+32
  const int vd = lane;                               // V: d index
  const int baseC = ((wave & 1) << 4) + ((wave >> 1) << 2);  // perm col base
  short8 kst[2];
  short4v vst[4];

#define LOADT(kbx)                                                                 \
  do {                                                                             \
    const int kr0_ = tok0 + ((kbx) << 6);                                          \
    _Pragma("unroll") for (int it = 0; it < 2; ++it)                               \
        kst[it] = *(const short8*)&K[(size_t)(kr0_ + krow + it * 32) * 1024 +      \
                                     h * 64 + kcol];                               \
    _Pragma("unroll") for (int it = 0; it < 2; ++it) {                             \
      const unsigned short* vp_ =                                                  \
          &V[(size_t)(kr0_ + ((wave + it * 4) << 3)) * 1024 + h * 64 + vd];        \
      _Pragma("unroll") for (int i = 0; i < 4; ++i) {                              \
        vst[it * 2][i]     = (short)vp_[(size_t)i * 1024];                         \
        vst[it * 2 + 1][i] = (short)vp_[(size_t)(i + 4) * 1024];                   \
      }                                                                            \
    }                                                                              \
  } while (0)

#define STORET(bi)                                                                 \
  do {                                                                             \
    _Pragma("unroll") for (int it = 0; it < 2; ++it)                               \
        *(short8*)&Ks[bi][krow + it * 32][kcol] = kst[it];                         \
    *(short4v*)&Vt[bi][vd][baseC]          = vst[0];                               \
    *(short4v*)&Vt[bi][vd][baseC + 8]      = vst[1];                               \
    *(short4v*)&Vt[bi][vd][32 + baseC]     = vst[2];                               \
    *(short4v*)&Vt[bi][vd][32 + baseC + 8] = vst[3];                               \
  } while (0)

  const int nkb = (qb + 1) << 1;
  LOADT(0);
  STORET(0);
  __syncthreads();

  for (int kb = 0; kb < nkb; ++kb) {
    const int cur = kb & 1;
    const bool more = (kb + 1 < nkb);
    if (more) LOADT(kb + 1);  // VMEM in flight during compute (T14)

    // QK^T for BOTH m-tiles: kf read once (8 ds_reads, shared)
    float p[2][4][4];
#pragma unroll
    for (int ct = 0; ct < 4; ++ct) {
      short8 kf0 = *(const short8*)&Ks[cur][ct * 16 + lr][lk8];
      short8 kf1 = *(const short8*)&Ks[cur][ct * 16 + lr][32 + lk8];
      f32x4 s0 = {}, s1 = {};
      s0 = MFMA(kf0, qf[0][0], s0);
      s0 = MFMA(kf1, qf[0][1], s0);
      s1 = MFMA(kf0, qf[1][0], s1);
      s1 = MFMA(kf1, qf[1][1], s1);
#pragma unroll
      for (int r = 0; r < 4; ++r) { p[0][ct][r] = s0[r]; p[1][ct][r] = s1[r]; }
    }
    if (kb >= 2 * qb) {  // diagonal region: mask key > q
#pragma unroll
      for (int mt = 0; mt < 2; ++mt) {
        const int qg = qrow0 + mt * 16 + lr;
#pragma unroll
        for (int ct = 0; ct < 4; ++ct)
#pragma unroll
          for (int r = 0; r < 4; ++r) {
            int kg = (kb << 6) + ct * 16 + rg + r;
            if (kg > qg) p[mt][ct][r] = -1e30f;
          }
      }
    }
    // softmax: lazy row-max + per-lane partial l (no cross-lane common path)
    unsigned pk[2][4][2];
#pragma unroll
    for (int mt = 0; mt < 2; ++mt) {
      float lmx = p[mt][0][0];   // lane-local max (16 own values)
#pragma unroll
      for (int ct = 0; ct < 4; ++ct)
#pragma unroll
        for (int r = 0; r < 4; ++r) lmx = fmaxf(lmx, p[mt][ct][r]);
      if (__any(lmx > m[mt] + 8.f)) {
        float mx = lmx;
        mx = fmaxf(mx, __shfl_xor(mx, 16));
        mx = fmaxf(mx, __shfl_xor(mx, 32));
        float mn = fmaxf(m[mt], mx);
        float alpha = __builtin_amdgcn_exp2f(m[mt] - mn);
        m[mt] = mn;
        l[mt] *= alpha;
        float a4[4];
#pragma unroll
        for (int r = 0; r < 4; ++r) a4[r] = __shfl(alpha, rg + r);
#pragma unroll
        for (int dt = 0; dt < 4; ++dt)
#pragma unroll
          for (int r = 0; r < 4; ++r) acc[mt][dt][r] *= a4[r];
      }
      float rs = 0.f;
#pragma unroll
      for (int ct = 0; ct < 4; ++ct) {
#pragma unroll
        for (int r = 0; r < 4; ++r) {
          p[mt][ct][r] = __builtin_amdgcn_exp2f(p[mt][ct][r] - m[mt]);
          rs += p[mt][ct][r];
        }
        pk[mt][ct][0] = cvt_pk_bf16(p[mt][ct][0], p[mt][ct][1]);
        pk[mt][ct][1] = cvt_pk_bf16(p[mt][ct][2], p[mt][ct][3]);
      }
      l[mt] += rs;               // lane-local partial; reduced once at the end
    }
    // PV for BOTH m-tiles: vf read once (8 ds_reads, shared)
#pragma unroll
    for (int kk = 0; kk < 2; ++kk) {
      union { unsigned u[4]; short8 v; } pa0, pa1;
      pa0.u[0] = pk[0][kk * 2][0];     pa0.u[1] = pk[0][kk * 2][1];
      pa0.u[2] = pk[0][kk * 2 + 1][0]; pa0.u[3] = pk[0][kk * 2 + 1][1];
      pa1.u[0] = pk[1][kk * 2][0];     pa1.u[1] = pk[1][kk * 2][1];
      pa1.u[2] = pk[1][kk * 2 + 1][0]; pa1.u[3] = pk[1][kk * 2 + 1][1];
#pragma unroll
      for (int dt = 0; dt < 4; ++dt) {
        short8 vf = *(const short8*)&Vt[cur][dt * 16 + lr][kk * 32 + lk8];
        acc[0][dt] = MFMA(pa0.v, vf, acc[0][dt]);
        acc[1][dt] = MFMA(pa1.v, vf, acc[1][dt]);
      }
    }

    if (more) {
      STORET(cur ^ 1);
      __syncthreads();
    }
  }
#undef LOADT
#undef STORET

#pragma unroll
  for (int mt = 0; mt < 2; ++mt) {
    float lsum = l[mt];
    lsum += __shfl_xor(lsum, 16);
    lsum += __shfl_xor(lsum, 32);
    float linv = 1.0f / lsum;
    float inv[4];
#pragma unroll
    for (int r = 0; r < 4; ++r) inv[r] = __shfl(linv, rg + r);
#pragma unroll
    for (int dt = 0; dt < 4; ++dt)
#pragma unroll
      for (int r = 0; r < 4; ++r) {
        int trow = tok0 + qrow0 + mt * 16 + rg + r;
        O[(size_t)trow * 1024 + h * 64 + dt * 16 + lr] = f2b(acc[mt][dt][r] * inv[r]);
      }
  }
}

extern "C" void kernel_launch(void* const* d_in, const int* in_sizes, int n_in,
                              void* d_out, int out_size, void* d_ws, size_t ws_size,
                              hipStream_t stream) {
  const float* hidden = (const float*)d_in[0];
  const float* q_w    = (const float*)d_in[1];
  const float* k_w    = (const float*)d_in[2];
  const float* v_w    = (const float*)d_in[3];
  const float* o_w    = (const float*)d_in[4];
  const float* cosb   = (const float*)d_in[5];
  const float* sinb   = (const float*)d_in[6];

  const size_t TD = (size_t)8192 * 1024;
  unsigned short* ws  = (unsigned short*)d_ws;
  unsigned short* Qb  = ws;
  unsigned short* Kb  = ws + TD;
  unsigned short* Vb  = ws + 2 * TD;
  unsigned short* hBF = ws + 3 * TD;        // hidden bf16; aliased as AO after QKV
  unsigned short* wBF = ws + 4 * TD;        // q,k,v,o weights bf16 (4 x 1M)

  convert_kernel<<<4096, 256, 0, stream>>>(hidden, q_w, k_w, v_w, o_w, hBF);
  gemm256<true><<<dim3(32, 24), 512, 0, stream>>>(hBF, wBF, Qb, cosb, sinb);
  attn_kernel<<<1024, 256, 0, stream>>>(Qb, Kb, Vb, hBF /*AO*/);
  gemm256<false><<<dim3(32, 8), 512, 0, stream>>>(
      hBF, wBF + 3 * 1048576, d_out, nullptr, nullptr);
}

// Round 24
// 125.134 us; speedup vs baseline: 4.7890x; 1.0435x over previous
//
#include <hip/hip_runtime.h>

typedef __attribute__((ext_vector_type(8))) short short8;
typedef __attribute__((ext_vector_type(4))) short short4v;
typedef __attribute__((ext_vector_type(4))) float f32x4;

#define MFMA(a, b, c) __builtin_amdgcn_mfma_f32_16x16x32_bf16((a), (b), (c), 0, 0, 0)
#define GLD16(g, l)                                                            \
  __builtin_amdgcn_global_load_lds(                                            \
      (const __attribute__((address_space(1))) void*)(g),                      \
      (__attribute__((address_space(3))) void*)(l), 16, 0, 0)

static __device__ __forceinline__ float b2f(unsigned short b) {
  union { unsigned u; float f; } u; u.u = ((unsigned)b) << 16; return u.f;
}
static __device__ __forceinline__ unsigned short f2b(float f) {
  union { float f; unsigned u; } u; u.f = f;
  unsigned r = u.u + 0x7FFFu + ((u.u >> 16) & 1u);
  return (unsigned short)(r >> 16);
}
// HW RNE pack: low16 = bf16(a), high16 = bf16(b). Same rounding as f2b.
static __device__ __forceinline__ unsigned cvt_pk_bf16(float a, float b) {
  unsigned r;
  asm("v_cvt_pk_bf16_f32 %0, %1, %2" : "=v"(r) : "v"(a), "v"(b));
  return r;
}

// fp32 -> bf16 convert: [hidden][q_w][k_w][v_w][o_w] -> contiguous bf16.
__global__ __launch_bounds__(256) void convert_kernel(
    const float* __restrict__ hidden,
    const float* __restrict__ qw, const float* __restrict__ kw,
    const float* __restrict__ vw, const float* __restrict__ ow,
    unsigned short* __restrict__ dst) {
  const int HID4 = 2097152, W4 = 262144, TOT = HID4 + 4 * W4;
  for (int i = blockIdx.x * 256 + threadIdx.x; i < TOT; i += gridDim.x * 256) {
    const float* src; int off;
    if (i < HID4) { src = hidden; off = i; }
    else {
      int j = i - HID4; int w = j >> 18; off = j & (W4 - 1);
      src = (w == 0) ? qw : (w == 1) ? kw : (w == 2) ? vw : ow;
    }
    float4 v = *(const float4*)&src[(size_t)off * 4];
    short4v s;
    s[0] = (short)f2b(v.x); s[1] = (short)f2b(v.y);
    s[2] = (short)f2b(v.z); s[3] = (short)f2b(v.w);
    *(short4v*)&dst[(size_t)i * 4] = s;
  }
}

// C[8192 x N] = A[8192 x 1024](bf16) * W^T (W [N x 1024] bf16 row-major).
// 256x128 tile, BK=32, 512 thr (8 waves 4Mx2N), 3 LDS buffers (72KB ->
// 2 blocks/CU), prefetch distance 2, counted vmcnt(3). Swizzle f(ra) =
// (ra>>1)&3: bank slots 4*(ra&1) + (hi4^f(ra)) cover all 8 exactly twice
// across 16 lanes -> 2-way aliasing (free). QKV=true: RoPE fused epilogue.
template <bool QKV>
__global__ __launch_bounds__(512, 4) void gemm256(
    const unsigned short* __restrict__ A,
    const unsigned short* __restrict__ W,
    void* __restrict__ Cv,
    const float* __restrict__ cosb, const float* __restrict__ sinb) {
  __shared__ __align__(16) unsigned short lds[36864];  // 3 x (A 8192 + B 4096)
  const int tid = threadIdx.x, wave = tid >> 6, lane = tid & 63;
  const int bm = blockIdx.x << 8, bnc = blockIdx.y << 7;
  const int wr = (wave >> 1) << 6, wc = (wave & 1) << 6;
  const int lr = lane & 15, hi4 = lane >> 4;
  const int rowb = tid >> 2;                        // 0..127
  const int cgA = (tid & 3) ^ ((rowb >> 1) & 3);    // pre-swizzled source col-group
  const unsigned short* aSrc = A + (size_t)(bm + rowb) * 1024 + (cgA << 3);
  const unsigned short* bSrc = W + (size_t)(bnc + rowb) * 1024 + (cgA << 3);

  f32x4 acc[4][4] = {};

#define STAGE(t, bi)                                                           \
  do {                                                                         \
    unsigned short* As_ = lds + (bi) * 12288;                                  \
    unsigned short* Bs_ = As_ + 8192;                                          \
    const int k0_ = (t) << 5;                                                  \
    _Pragma("unroll") for (int i = 0; i < 2; ++i)                              \
        GLD16(aSrc + (size_t)(i << 7) * 1024 + k0_,                            \
              As_ + (((i << 9) + tid) << 3));                                  \
    GLD16(bSrc + k0_, Bs_ + (tid << 3));                                       \
  } while (0)

  STAGE(0, 0);
  STAGE(1, 1);
  asm volatile("s_waitcnt vmcnt(3)" ::: "memory");  // tile 0 landed
  __builtin_amdgcn_s_barrier();
  __builtin_amdgcn_sched_barrier(0);

  int bi = 0;
#pragma unroll
  for (int t = 0; t < 32; ++t) {
    int pf = bi + 2; if (pf >= 3) pf -= 3;
    if (t < 30) STAGE(t + 2, pf);  // issue early; consumers passed barrier
    const unsigned short* As = lds + bi * 12288;
    const unsigned short* Bs = As + 8192;
    short8 af[4], bfr[4];
#pragma unroll
    for (int x = 0; x < 4; ++x) {
      int ra = wr + x * 16 + lr;
      af[x] = *(const short8*)&As[ra * 32 + ((hi4 ^ ((ra >> 1) & 3)) << 3)];
      int rb = wc + x * 16 + lr;
      bfr[x] = *(const short8*)&Bs[rb * 32 + ((hi4 ^ ((rb >> 1) & 3)) << 3)];
    }
    __builtin_amdgcn_s_setprio(1);
#pragma unroll
    for (int mm = 0; mm < 4; ++mm)
#pragma unroll
      for (int nn = 0; nn < 4; ++nn)
        acc[mm][nn] = MFMA(af[mm], bfr[nn], acc[mm][nn]);
    __builtin_amdgcn_s_setprio(0);
    __builtin_amdgcn_sched_barrier(0);
    if (t < 30) asm volatile("s_waitcnt vmcnt(3)" ::: "memory");  // t+1 landed
    else        asm volatile("s_waitcnt vmcnt(0)" ::: "memory");
    __builtin_amdgcn_s_barrier();
    __builtin_amdgcn_sched_barrier(0);
    if (++bi == 3) bi = 0;
  }
#undef STAGE

  const int rg = hi4 << 2;
  if constexpr (QKV) {
    const int grp = bnc >> 10;  // 0=Q 1=K 2=V
    unsigned short* Cbuf = (unsigned short*)Cv + (size_t)grp * 8388608;
    const int colbase = (bnc & 1023) + wc;
    if (grp < 2) {
      float* csf = (float*)lds;        // [256][32] fp32 = 32KB
      float* snf = csf + 8192;         // +32KB = 64KB <= 72KB
#pragma unroll
      for (int i = 0; i < 4; ++i) {
        int s = (i << 9) + tid;
        int row = s >> 3, c4 = (s & 7) << 2;
        GLD16(cosb + (size_t)(bm + row) * 64 + c4, csf + s * 4);
        GLD16(sinb + (size_t)(bm + row) * 64 + c4, snf + s * 4);
      }
      asm volatile("s_waitcnt vmcnt(0)" ::: "memory");
      __builtin_amdgcn_s_barrier();
      __builtin_amdgcn_sched_barrier(0);
      const float sc = (grp == 0) ? 0.18033688011112042f : 1.0f;  // 0.125*log2e
#pragma unroll
      for (int mm = 0; mm < 4; ++mm)
#pragma unroll
        for (int r = 0; r < 4; ++r) {
          int rloc = wr + mm * 16 + rg + r;
          size_t rowoff = (size_t)(bm + rloc) * 1024;
#pragma unroll
          for (int nn = 0; nn < 2; ++nn) {
            int d = nn * 16 + lr;
            float c = csf[rloc * 32 + d], s2 = snf[rloc * 32 + d];
            float lo = acc[mm][nn][r], hi = acc[mm][nn + 2][r];
            Cbuf[rowoff + colbase + nn * 16 + lr]      = f2b((lo * c - hi * s2) * sc);
            Cbuf[rowoff + colbase + nn * 16 + lr + 32] = f2b((hi * c + lo * s2) * sc);
          }
        }
    } else {
#pragma unroll
      for (int mm = 0; mm < 4; ++mm)
#pragma unroll
        for (int nn = 0; nn < 4; ++nn)
#pragma unroll
          for (int r = 0; r < 4; ++r)
            Cbuf[(size_t)(bm + wr + mm * 16 + rg + r) * 1024 + colbase + nn * 16 + lr] =
                f2b(acc[mm][nn][r]);
    }
  } else {
    float* C = (float*)Cv;
#pragma unroll
    for (int mm = 0; mm < 4; ++mm)
#pragma unroll
      for (int nn = 0; nn < 4; ++nn)
#pragma unroll
        for (int r = 0; r < 4; ++r)
          C[(size_t)(bm + wr + mm * 16 + rg + r) * 1024 + bnc + wc + nn * 16 + lr] =
              acc[mm][nn][r];
  }
}

// Causal flash attention v11 (round-18 exact, best measured): 1024-block LPT,
// 3 blocks/CU, swapped-QK^T in-register softmax, cvt_pk pack, permuted V,
// KVBLK=64 dbuf, lazy row-max, per-lane partial l, exp2 domain.
__global__ __launch_bounds__(256, 3) void attn_kernel(
    const unsigned short* __restrict__ Q,
    const unsigned short* __restrict__ K,
    const unsigned short* __restrict__ V,
    unsigned short* __restrict__ O) {
  __shared__ unsigned short Ks[2][64][72];   // [buf][key][d]
  __shared__ unsigned short Vt[2][64][72];   // [buf][d][permuted key col]
  const int tid = threadIdx.x, wave = tid >> 6, lane = tid & 63;
  const int idx = blockIdx.x;
  const int bh = idx & 127;
  const int b = bh >> 4, h = bh & 15;
  const int qb = 7 - (idx >> 7);             // heavy-first (LPT)
  const int tok0 = b << 10;
  const int lr = lane & 15, hi4 = lane >> 4, lk8 = hi4 << 3;
  const int rg = hi4 << 2;
  const int qrow0 = (qb << 7) + (wave << 5); // 32 rows per wave

  short8 qf[2][2];
#pragma unroll
  for (int mt = 0; mt < 2; ++mt) {
    const unsigned short* qp = &Q[(size_t)(tok0 + qrow0 + mt * 16 + lr) * 1024 + h * 64];
#pragma unroll
    for (int kk = 0; kk < 2; ++kk) qf[mt][kk] = *(const short8*)&qp[kk * 32 + lk8];
  }

  f32x4 acc[2][4] = {};
  float m[2], l[2];                          // l = per-lane partial
#pragma unroll
  for (int mt = 0; mt < 2; ++mt) { m[mt] = -1e30f; l[mt] = 0.f; }

  const int krow = tid >> 3, kcol = (tid & 7) << 3;  // K: rows krow, krow+32
  const int vd = lane;                               // V: d index
  const int baseC = ((wave & 1) << 4) + ((wave >> 1) << 2);  // perm col base
  short8 kst[2];
  short4v vst[4];

#define LOADT(kbx)                                                                 \
  do {                                                                             \
    const int kr0_ = tok0 + ((kbx) << 6);                                          \
    _Pragma("unroll") for (int it = 0; it < 2; ++it)                               \
        kst[it] = *(const short8*)&K[(size_t)(kr0_ + krow + it * 32) * 1024 +      \
                                     h * 64 + kcol];                               \
    _Pragma("unroll") for (int it = 0; it < 2; ++it) {                             \
      const unsigned short* vp_ =                                                  \
          &V[(size_t)(kr0_ + ((wave + it * 4) << 3)) * 1024 + h * 64 + vd];        \
      _Pragma("unroll") for (int i = 0; i < 4; ++i) {                              \
        vst[it * 2][i]     = (short)vp_[(size_t)i * 1024];                         \
        vst[it * 2 + 1][i] = (short)vp_[(size_t)(i + 4) * 1024];                   \
      }                                                                            \
    }                                                                              \
  } while (0)

#define STORET(bi)                                                                 \
  do {                                                                             \
    _Pragma("unroll") for (int it = 0; it < 2; ++it)                               \
        *(short8*)&Ks[bi][krow + it * 32][kcol] = kst[it];                         \
    *(short4v*)&Vt[bi][vd][baseC]          = vst[0];                               \
    *(short4v*)&Vt[bi][vd][baseC + 8]      = vst[1];                               \
    *(short4v*)&Vt[bi][vd][32 + baseC]     = vst[2];                               \
    *(short4v*)&Vt[bi][vd][32 + baseC + 8] = vst[3];                               \
  } while (0)

  const int nkb = (qb + 1) << 1;
  LOADT(0);
  STORET(0);
  __syncthreads();

  for (int kb = 0; kb < nkb; ++kb) {
    const int cur = kb & 1;
    const bool more = (kb + 1 < nkb);
    if (more) LOADT(kb + 1);  // VMEM in flight during compute (T14)

    // QK^T for BOTH m-tiles: kf read once (8 ds_reads, shared)
    float p[2][4][4];
#pragma unroll
    for (int ct = 0; ct < 4; ++ct) {
      short8 kf0 = *(const short8*)&Ks[cur][ct * 16 + lr][lk8];
      short8 kf1 = *(const short8*)&Ks[cur][ct * 16 + lr][32 + lk8];
      f32x4 s0 = {}, s1 = {};
      s0 = MFMA(kf0, qf[0][0], s0);
      s0 = MFMA(kf1, qf[0][1], s0);
      s1 = MFMA(kf0, qf[1][0], s1);
      s1 = MFMA(kf1, qf[1][1], s1);
#pragma unroll
      for (int r = 0; r < 4; ++r) { p[0][ct][r] = s0[r]; p[1][ct][r] = s1[r]; }
    }
    if (kb >= 2 * qb) {  // diagonal region: mask key > q
#pragma unroll
      for (int mt = 0; mt < 2; ++mt) {
        const int qg = qrow0 + mt * 16 + lr;
#pragma unroll
        for (int ct = 0; ct < 4; ++ct)
#pragma unroll
          for (int r = 0; r < 4; ++r) {
            int kg = (kb << 6) + ct * 16 + rg + r;
            if (kg > qg) p[mt][ct][r] = -1e30f;
          }
      }
    }
    // softmax: lazy row-max + per-lane partial l (no cross-lane common path)
    unsigned pk[2][4][2];
#pragma unroll
    for (int mt = 0; mt < 2; ++mt) {
      float lmx = p[mt][0][0];   // lane-local max (16 own values)
#pragma unroll
      for (int ct = 0; ct < 4; ++ct)
#pragma unroll
        for (int r = 0; r < 4; ++r) lmx = fmaxf(lmx, p[mt][ct][r]);
      if (__any(lmx > m[mt] + 8.f)) {
        float mx = lmx;
        mx = fmaxf(mx, __shfl_xor(mx, 16));
        mx = fmaxf(mx, __shfl_xor(mx, 32));
        float mn = fmaxf(m[mt], mx);
        float alpha = __builtin_amdgcn_exp2f(m[mt] - mn);
        m[mt] = mn;
        l[mt] *= alpha;
        float a4[4];
#pragma unroll
        for (int r = 0; r < 4; ++r) a4[r] = __shfl(alpha, rg + r);
#pragma unroll
        for (int dt = 0; dt < 4; ++dt)
#pragma unroll
          for (int r = 0; r < 4; ++r) acc[mt][dt][r] *= a4[r];
      }
      float rs = 0.f;
#pragma unroll
      for (int ct = 0; ct < 4; ++ct) {
#pragma unroll
        for (int r = 0; r < 4; ++r) {
          p[mt][ct][r] = __builtin_amdgcn_exp2f(p[mt][ct][r] - m[mt]);
          rs += p[mt][ct][r];
        }
        pk[mt][ct][0] = cvt_pk_bf16(p[mt][ct][0], p[mt][ct][1]);
        pk[mt][ct][1] = cvt_pk_bf16(p[mt][ct][2], p[mt][ct][3]);
      }
      l[mt] += rs;               // lane-local partial; reduced once at the end
    }
    // PV for BOTH m-tiles: vf read once (8 ds_reads, shared)
#pragma unroll
    for (int kk = 0; kk < 2; ++kk) {
      union { unsigned u[4]; short8 v; } pa0, pa1;
      pa0.u[0] = pk[0][kk * 2][0];     pa0.u[1] = pk[0][kk * 2][1];
      pa0.u[2] = pk[0][kk * 2 + 1][0]; pa0.u[3] = pk[0][kk * 2 + 1][1];
      pa1.u[0] = pk[1][kk * 2][0];     pa1.u[1] = pk[1][kk * 2][1];
      pa1.u[2] = pk[1][kk * 2 + 1][0]; pa1.u[3] = pk[1][kk * 2 + 1][1];
#pragma unroll
      for (int dt = 0; dt < 4; ++dt) {
        short8 vf = *(const short8*)&Vt[cur][dt * 16 + lr][kk * 32 + lk8];
        acc[0][dt] = MFMA(pa0.v, vf, acc[0][dt]);
        acc[1][dt] = MFMA(pa1.v, vf, acc[1][dt]);
      }
    }

    if (more) {
      STORET(cur ^ 1);
      __syncthreads();
    }
  }
#undef LOADT
#undef STORET

#pragma unroll
  for (int mt = 0; mt < 2; ++mt) {
    float lsum = l[mt];
    lsum += __shfl_xor(lsum, 16);
    lsum += __shfl_xor(lsum, 32);
    float linv = 1.0f / lsum;
    float inv[4];
#pragma unroll
    for (int r = 0; r < 4; ++r) inv[r] = __shfl(linv, rg + r);
#pragma unroll
    for (int dt = 0; dt < 4; ++dt)
#pragma unroll
      for (int r = 0; r < 4; ++r) {
        int trow = tok0 + qrow0 + mt * 16 + rg + r;
        O[(size_t)trow * 1024 + h * 64 + dt * 16 + lr] = f2b(acc[mt][dt][r] * inv[r]);
      }
  }
}

extern "C" void kernel_launch(void* const* d_in, const int* in_sizes, int n_in,
                              void* d_out, int out_size, void* d_ws, size_t ws_size,
                              hipStream_t stream) {
  const float* hidden = (const float*)d_in[0];
  const float* q_w    = (const float*)d_in[1];
  const float* k_w    = (const float*)d_in[2];
  const float* v_w    = (const float*)d_in[3];
  const float* o_w    = (const float*)d_in[4];
  const float* cosb   = (const float*)d_in[5];
  const float* sinb   = (const float*)d_in[6];

  const size_t TD = (size_t)8192 * 1024;
  unsigned short* ws  = (unsigned short*)d_ws;
  unsigned short* Qb  = ws;
  unsigned short* Kb  = ws + TD;
  unsigned short* Vb  = ws + 2 * TD;
  unsigned short* hBF = ws + 3 * TD;        // hidden bf16; aliased as AO after QKV
  unsigned short* wBF = ws + 4 * TD;        // q,k,v,o weights bf16 (4 x 1M)

  convert_kernel<<<4096, 256, 0, stream>>>(hidden, q_w, k_w, v_w, o_w, hBF);
  gemm256<true><<<dim3(32, 24), 512, 0, stream>>>(hBF, wBF, Qb, cosb, sinb);
  attn_kernel<<<1024, 256, 0, stream>>>(Qb, Kb, Vb, hBF /*AO*/);
  gemm256<false><<<dim3(32, 8), 512, 0, stream>>>(
      hBF, wBF + 3 * 1048576, d_out, nullptr, nullptr);
}